// Round 7
// baseline (109.859 us; speedup 1.0000x reference)
//
#include <hip/hip_runtime.h>

#define IN_DIM  4096
#define OUT_DIM 4096
#define RANK    16
#define NBLK    16
#define KDIM    256   // NBLK*RANK

typedef __attribute__((ext_vector_type(8))) __bf16 bf16x8;
typedef __attribute__((ext_vector_type(4))) __bf16 bf16x4;
typedef __attribute__((ext_vector_type(4))) float  f32x4;

// ---------------------------------------------------------------------------
// Pack layouts (MFMA 16x16x32 fragment order), granularity = bf16x8 (16B):
//   PackA[mt(128)][ko(32)][c(16)] : 8 bf16 = T[mt*16+c][ko*8+j]   (A row=c)
//   PackB[nt(256)][ko(32)][c(16)] : 8 bf16 = Ahat[ko*8+j][nt*16+c](B col=c)
//   PackV[i(16)][ks(8)][qt(4)][c(16)] : 8 bf16 = Vt[i][ks*32+qt*8+j][c]
// apply GEMM: out = [Ahi|Alo] (m x 2K) @ [Bhi;Bhi] (2K x n)  (K'=512 concat;
// T kept to ~16-bit mantissa, weights single-bf16).
// ---------------------------------------------------------------------------

__device__ __forceinline__ void split_bf16(float v, __bf16& h, __bf16& l) {
    h = (__bf16)v;
    l = (__bf16)(v - (float)h);
}

// blocks 0..511: B-pack (Ahat = S*U, bf16-hi only).  blocks 512..543: Vt-pack.
__global__ __launch_bounds__(256) void build_packs(const float* __restrict__ S,
                                                   const float* __restrict__ U,
                                                   const float* __restrict__ Vt,
                                                   bf16x8* __restrict__ Bhi,
                                                   bf16x8* __restrict__ Vhi,
                                                   bf16x8* __restrict__ Vlo) {
    const int blk = blockIdx.x;
    if (blk < 512) {
        int t  = blk * 256 + threadIdx.x;  // = (nt*32 + ko)*16 + c
        int c  = t & 15;
        int ko = (t >> 4) & 31;
        int nt = t >> 9;
        int o  = nt >> 4;
        int i  = ko >> 1;
        int q  = ((nt & 15) << 4) | c;
        int r0 = (ko & 1) << 3;
        const float* Sp = S + ((o * NBLK + i) * RANK + r0);
        const float* Up = U + (size_t)o * RANK * 256 + q;   // + r*256
        bf16x8 hi;
#pragma unroll
        for (int j = 0; j < 8; ++j) {
            float w = Sp[j] * Up[(size_t)(r0 + j) * 256];
            hi[j] = (__bf16)w;
        }
        Bhi[t] = hi;
    } else {
        int t  = (blk - 512) * 256 + threadIdx.x;  // = ((i*8+ks)*4+qt)*16 + c
        int c  = t & 15;
        int p0 = (t >> 4) << 3;                    // (ks*32 + qt*8) within block i
        int i  = t >> 9;
        int pbase = (p0 & 255);
        const float* vp = Vt + ((size_t)(i * 256 + pbase)) * RANK + c;
        bf16x8 hi, lo;
#pragma unroll
        for (int j = 0; j < 8; ++j) {
            float w = vp[(size_t)j * RANK];
            __bf16 h, l;
            split_bf16(w, h, l);
            hi[j] = h; lo[j] = l;
        }
        Vhi[t] = hi;
        Vlo[t] = lo;
    }
}

// Stage A via MFMA:  D[r][m] = sum_p Vt[i][p][r] * x[m][p]  (per (mt, i) job)
__global__ __launch_bounds__(256) void factor_mfma(const float* __restrict__ x,
                                                   const bf16x8* __restrict__ Vhi,
                                                   const bf16x8* __restrict__ Vlo,
                                                   bf16x4* __restrict__ Ahi4,
                                                   bf16x4* __restrict__ Alo4,
                                                   float* __restrict__ rowsum_p,
                                                   int M) {
    const int tid = threadIdx.x;
    const int l   = tid & 63;
    const int w   = tid >> 6;
    const int job = blockIdx.x * 4 + w;     // (mt, i)
    const int i   = job & 15;
    const int mt  = job >> 4;
    const int row = l & 15;                 // m within tile (B col)
    const int qt  = l >> 4;                 // k-quarter

    const float* xp = x + (size_t)(mt * 16 + row) * IN_DIM + i * 256 + qt * 8;

    f32x4 acc = {0.f, 0.f, 0.f, 0.f};
    float rs = 0.f;
#pragma unroll
    for (int ks = 0; ks < 8; ++ks) {
        float4 a = *reinterpret_cast<const float4*>(xp + ks * 32);
        float4 b = *reinterpret_cast<const float4*>(xp + ks * 32 + 4);
        rs += (a.x + a.y) + (a.z + a.w) + (b.x + b.y) + (b.z + b.w);
        float vv[8] = {a.x, a.y, a.z, a.w, b.x, b.y, b.z, b.w};
        bf16x8 xh, xl;
#pragma unroll
        for (int jj = 0; jj < 8; ++jj) {
            __bf16 h, lo_;
            split_bf16(vv[jj], h, lo_);
            xh[jj] = h; xl[jj] = lo_;
        }
        size_t vidx = (size_t)((i * 8 + ks) * 4 + qt) * 16 + row;
        bf16x8 vh = Vhi[vidx];
        bf16x8 vl = Vlo[vidx];
        acc = __builtin_amdgcn_mfma_f32_16x16x32_bf16(vh, xh, acc, 0, 0, 0);
        acc = __builtin_amdgcn_mfma_f32_16x16x32_bf16(vh, xl, acc, 0, 0, 0);
        acc = __builtin_amdgcn_mfma_f32_16x16x32_bf16(vl, xh, acc, 0, 0, 0);
    }

    rs += __shfl_xor(rs, 16, 64);
    rs += __shfl_xor(rs, 32, 64);
    if (l < 16)
        rowsum_p[(size_t)i * M + mt * 16 + l] = rs;

    bf16x4 hi, lo;
#pragma unroll
    for (int reg = 0; reg < 4; ++reg) {
        __bf16 h, lo_;
        split_bf16(acc[reg], h, lo_);
        hi[reg] = h; lo[reg] = lo_;
    }
    size_t o4 = ((size_t)(mt * 32 + i * 2 + (l >> 5)) * 16 + row) * 2 + ((l >> 4) & 1);
    Ahi4[o4] = hi;
    Alo4[o4] = lo;
}

// out = [Ah|Al] @ [Bh;Bh] + (1+rowsum[m])*bias[n].
// Tile 128m x 256n, 512 thr (8 waves 2x4, each 64m x 64n), grid 256 = 1/CU.
// K=256 in 4 steps of 64; LDS/step = A 32KB (hi+lo) + B 32KB = 64KB; dbuf 128KB.
// Per wave per step: 64 MFMA : 24 ds_read_b128 : 8 global_load_lds.
__global__ __launch_bounds__(512, 2) void apply_mfma(const bf16x8* __restrict__ Ahi,
                                                     const bf16x8* __restrict__ Alo,
                                                     const bf16x8* __restrict__ Bhi,
                                                     const float* __restrict__ rowsum_p,
                                                     const float* __restrict__ bias,
                                                     float* __restrict__ out, int M) {
    __shared__ bf16x8 smem[2][4096];   // [buf][A-hi 0..1023 | A-lo 1024..2047 | B 2048..4095]
    __shared__ float rstot_s[128];

    const int nb  = blockIdx.x;
    const int q   = gridDim.x >> 3;             // 32 (grid 256, %8==0)
    const int lg  = (nb & 7) * q + (nb >> 3);   // XCD-contiguous logical id
    const int mr  = lg & 15;
    const int nc  = lg >> 4;                    // 2 consecutive nc per XCD
    const int m0  = mr * 128, n0 = nc * 256;
    const int mtb0 = m0 >> 4;                   // 8 mt-tiles
    const int ntb0 = n0 >> 4;                   // 16 nt-tiles

    const int tid = threadIdx.x;
    const int l   = tid & 63;
    const int w   = __builtin_amdgcn_readfirstlane(tid >> 6);  // 0..7
    const int wm  = w & 1, wn = w >> 1;         // 2x4 waves: 64m x 64n each
    const int kq  = l >> 4, c = l & 15;

    // stage one 64KB K-step chunk (K=64 -> ko0 = 8*s_) into buffer buf_;
    // 8 wave-loads (1KB each) per wave; LDS dest linear in lane order.
#define STAGE(s_, buf_)                                                              \
    {                                                                                \
        _Pragma("unroll")                                                            \
        for (int j = 0; j < 8; ++j) {                                                \
            const int u = w * 8 + j;                                                 \
            const bf16x8* gbase;                                                     \
            unsigned loff;                                                           \
            if (u < 16) {                                                            \
                gbase = Ahi + ((size_t)((mtb0 + (u >> 1)) * 32 + 8 * (s_)            \
                                        + (u & 1) * 4) * 16);                        \
                loff  = (unsigned)(((u >> 1) * 8 + (u & 1) * 4) * 16);               \
            } else if (u < 32) {                                                     \
                const int v = u - 16;                                                \
                gbase = Alo + ((size_t)((mtb0 + (v >> 1)) * 32 + 8 * (s_)            \
                                        + (v & 1) * 4) * 16);                        \
                loff  = 1024u + (unsigned)(((v >> 1) * 8 + (v & 1) * 4) * 16);       \
            } else {                                                                 \
                const int v = u - 32;                                                \
                gbase = Bhi + ((size_t)((ntb0 + (v >> 1)) * 32 + 8 * (s_)            \
                                        + (v & 1) * 4) * 16);                        \
                loff  = 2048u + (unsigned)(((v >> 1) * 8 + (v & 1) * 4) * 16);       \
            }                                                                        \
            __builtin_amdgcn_global_load_lds(                                        \
                (const __attribute__((address_space(1))) unsigned*)(gbase + l),      \
                (__attribute__((address_space(3))) unsigned*)&smem[buf_][loff],      \
                16, 0, 0);                                                           \
        }                                                                            \
    }

    f32x4 acc[4][4];
#pragma unroll
    for (int f = 0; f < 4; ++f)
#pragma unroll
        for (int nf = 0; nf < 4; ++nf) acc[f][nf] = f32x4{0.f, 0.f, 0.f, 0.f};

    STAGE(0, 0);
    if (tid < 128) {
        float ssum = 1.0f;
#pragma unroll
        for (int i = 0; i < NBLK; ++i) ssum += rowsum_p[(size_t)i * M + m0 + tid];
        rstot_s[tid] = ssum;
    }
    __syncthreads();

    for (int s = 0; s < 4; ++s) {
        if (s < 3) STAGE(s + 1, (s + 1) & 1);
        const bf16x8* sb = smem[s & 1];
#pragma unroll
        for (int ksl = 0; ksl < 2; ++ksl) {
            bf16x8 ah[4], al[4];
#pragma unroll
            for (int f = 0; f < 4; ++f) {
                const int mt = wm * 4 + f;
                ah[f] = sb[(mt * 8 + ksl * 4 + kq) * 16 + c];
                al[f] = sb[1024 + (mt * 8 + ksl * 4 + kq) * 16 + c];
            }
#pragma unroll
            for (int nf = 0; nf < 4; ++nf) {
                const int nt = wn * 4 + nf;
                bf16x8 bh = sb[2048 + (nt * 8 + ksl * 4 + kq) * 16 + c];
#pragma unroll
                for (int f = 0; f < 4; ++f) {
                    acc[f][nf] = __builtin_amdgcn_mfma_f32_16x16x32_bf16(ah[f], bh, acc[f][nf], 0, 0, 0);
                    acc[f][nf] = __builtin_amdgcn_mfma_f32_16x16x32_bf16(al[f], bh, acc[f][nf], 0, 0, 0);
                }
            }
        }
        __syncthreads();
    }
#undef STAGE

    // epilogue: out[m][n] = acc + rstot[m]*bias[n]   (C/D: row=kq*4+reg, col=c)
#pragma unroll
    for (int f = 0; f < 4; ++f) {
        const int rloc = wm * 64 + f * 16 + kq * 4;
        const int rowb = m0 + rloc;
        float rsv[4];
#pragma unroll
        for (int reg = 0; reg < 4; ++reg) rsv[reg] = rstot_s[rloc + reg];
#pragma unroll
        for (int nf = 0; nf < 4; ++nf) {
            const int n = n0 + wn * 64 + nf * 16 + c;
            const float bv = bias[n];
#pragma unroll
            for (int reg = 0; reg < 4; ++reg)
                out[(size_t)(rowb + reg) * OUT_DIM + n] = acc[f][nf][reg] + rsv[reg] * bv;
        }
    }
}

extern "C" void kernel_launch(void* const* d_in, const int* in_sizes, int n_in,
                              void* d_out, int out_size, void* d_ws, size_t ws_size,
                              hipStream_t stream) {
    const float* x    = (const float*)d_in[0];
    const float* S    = (const float*)d_in[1];
    const float* U    = (const float*)d_in[2];
    const float* Vt   = (const float*)d_in[3];
    const float* bias = (const float*)d_in[4];
    float* out = (float*)d_out;
    const int M = in_sizes[0] / IN_DIM;   // 2048

    char* ws = (char*)d_ws;
    bf16x8* Bhi     = (bf16x8*)ws;                                    // 2 MB
    bf16x8* Ahi     = (bf16x8*)(ws + (2u << 20));                     // 1 MB
    bf16x8* Alo     = (bf16x8*)(ws + (3u << 20));                     // 1 MB
    bf16x8* Vhi     = (bf16x8*)(ws + (4u << 20));                     // 128 KB
    bf16x8* Vlo     = (bf16x8*)(ws + (4u << 20) + (128u << 10));      // 128 KB
    float* rowsum_p = (float*)(ws + (4u << 20) + (256u << 10));       // 128 KB

    build_packs<<<544, 256, 0, stream>>>(S, U, Vt, Bhi, Vhi, Vlo);
    factor_mfma<<<M / 4, 256, 0, stream>>>(x, Vhi, Vlo,
                                           (bf16x4*)Ahi, (bf16x4*)Alo, rowsum_p, M);
    apply_mfma<<<(M / 128) * (OUT_DIM / 256), 512, 0, stream>>>(
        Ahi, Alo, Bhi, rowsum_p, bias, out, M);
}

// Round 8
// 104.445 us; speedup vs baseline: 1.0518x; 1.0518x over previous
//
#include <hip/hip_runtime.h>

#define IN_DIM  4096
#define OUT_DIM 4096
#define RANK    16
#define NBLK    16
#define KDIM    256   // NBLK*RANK

typedef __attribute__((ext_vector_type(8))) __bf16 bf16x8;
typedef __attribute__((ext_vector_type(4))) __bf16 bf16x4;
typedef __attribute__((ext_vector_type(4))) float  f32x4;

// ---------------------------------------------------------------------------
// Pack layouts (MFMA 16x16x32 fragment order), granularity = bf16x8 (16B):
//   PackA[mt(128)][ko(32)][c(16)] : 8 bf16 = T[mt*16+c][ko*8+j]   (A row=c)
//   PackB[nt(256)][ko(32)][c(16)] : 8 bf16 = Ahat[ko*8+j][nt*16+c](B col=c)
// apply GEMM: out = [Ahi|Alo] (m x 2K) @ [Bhi;Bhi] (2K x n)  (K'=512 concat;
// T kept to ~16-bit mantissa, weights single-bf16).
// ---------------------------------------------------------------------------

__device__ __forceinline__ void split_bf16(float v, __bf16& h, __bf16& l) {
    h = (__bf16)v;
    l = (__bf16)(v - (float)h);
}

// Fused: blocks [0, M/4)      : factor  T = x @ Vt-blocks  (MFMA, raw-Vt split)
//        blocks [M/4, M/4+512): B-pack  Ahat = S*U -> bf16 fragments
__global__ __launch_bounds__(256) void fused_factor_pack(const float* __restrict__ x,
                                                         const float* __restrict__ S,
                                                         const float* __restrict__ U,
                                                         const float* __restrict__ Vt,
                                                         bf16x4* __restrict__ Ahi4,
                                                         bf16x4* __restrict__ Alo4,
                                                         bf16x8* __restrict__ Bhi,
                                                         float* __restrict__ rowsum_p,
                                                         int M) {
    const int nfac = M >> 2;   // 512 factor blocks
    const int blk  = blockIdx.x;
    const int tid  = threadIdx.x;

    if (blk < nfac) {
        // ---- factor: D[r][m] = sum_p Vt[i][p][r] * x[m][p]  (job = (mt, i)) ----
        const int l   = tid & 63;
        const int w   = tid >> 6;
        const int job = blk * 4 + w;
        const int i   = job & 15;
        const int mt  = job >> 4;
        const int row = l & 15;                 // m within tile (B col) / r-row source col
        const int qt  = l >> 4;                 // k-quarter

        const float* xp  = x + (size_t)(mt * 16 + row) * IN_DIM + i * 256 + qt * 8;
        // Vt[i][qt*8 + ks*32 + j][row], j-stride = RANK floats
        const float* vtp = Vt + ((size_t)(i * 256 + qt * 8)) * RANK + row;

        f32x4 acc = {0.f, 0.f, 0.f, 0.f};
        float rs = 0.f;
#pragma unroll
        for (int ks = 0; ks < 8; ++ks) {
            float4 a = *reinterpret_cast<const float4*>(xp + ks * 32);
            float4 b = *reinterpret_cast<const float4*>(xp + ks * 32 + 4);
            rs += (a.x + a.y) + (a.z + a.w) + (b.x + b.y) + (b.z + b.w);
            float vv[8] = {a.x, a.y, a.z, a.w, b.x, b.y, b.z, b.w};
            bf16x8 xh, xl;
#pragma unroll
            for (int jj = 0; jj < 8; ++jj) {
                __bf16 h, lo_;
                split_bf16(vv[jj], h, lo_);
                xh[jj] = h; xl[jj] = lo_;
            }
            bf16x8 vh, vl;
#pragma unroll
            for (int jj = 0; jj < 8; ++jj) {
                float v = vtp[(size_t)(ks * 32 + jj) * RANK];
                __bf16 h, lo_;
                split_bf16(v, h, lo_);
                vh[jj] = h; vl[jj] = lo_;
            }
            acc = __builtin_amdgcn_mfma_f32_16x16x32_bf16(vh, xh, acc, 0, 0, 0);
            acc = __builtin_amdgcn_mfma_f32_16x16x32_bf16(vh, xl, acc, 0, 0, 0);
            acc = __builtin_amdgcn_mfma_f32_16x16x32_bf16(vl, xh, acc, 0, 0, 0);
        }

        rs += __shfl_xor(rs, 16, 64);
        rs += __shfl_xor(rs, 32, 64);
        if (l < 16)
            rowsum_p[(size_t)i * M + mt * 16 + l] = rs;

        bf16x4 hi, lo;
#pragma unroll
        for (int reg = 0; reg < 4; ++reg) {
            __bf16 h, lo_;
            split_bf16(acc[reg], h, lo_);
            hi[reg] = h; lo[reg] = lo_;
        }
        size_t o4 = ((size_t)(mt * 32 + i * 2 + (l >> 5)) * 16 + row) * 2 + ((l >> 4) & 1);
        Ahi4[o4] = hi;
        Alo4[o4] = lo;
    } else {
        // ---- B-pack: Ahat[(i,r)][(o,q)] = S[o,i,r]*U[o,r,q] -> bf16-hi ----
        int t  = (blk - nfac) * 256 + tid;  // = (nt*32 + ko)*16 + c
        int c  = t & 15;
        int ko = (t >> 4) & 31;
        int nt = t >> 9;
        int o  = nt >> 4;
        int i  = ko >> 1;
        int q  = ((nt & 15) << 4) | c;
        int r0 = (ko & 1) << 3;
        const float* Sp = S + ((o * NBLK + i) * RANK + r0);
        const float* Up = U + (size_t)o * RANK * 256 + q;   // + r*256
        bf16x8 hi;
#pragma unroll
        for (int j = 0; j < 8; ++j) {
            float w = Sp[j] * Up[(size_t)(r0 + j) * 256];
            hi[j] = (__bf16)w;
        }
        Bhi[t] = hi;
    }
}

// out = [Ah|Al] @ [Bh;Bh] + (1+rowsum[m])*bias[n].
// Tile 128m x 128n, 512 blocks (3 blk/CU -> cross-block write/compute overlap),
// 4 waves (2x2, each 64m x 64n), K=256 in 8 steps of 32.
// LDS/step: A-hi 8KB + A-lo 8KB + B-hi 8KB = 24KB; dbuf 48KB.
__global__ __launch_bounds__(256, 3) void apply_mfma(const bf16x8* __restrict__ Ahi,
                                                     const bf16x8* __restrict__ Alo,
                                                     const bf16x8* __restrict__ Bhi,
                                                     const float* __restrict__ rowsum_p,
                                                     const float* __restrict__ bias,
                                                     float* __restrict__ out, int M) {
    __shared__ bf16x8 smem[2][1536];   // [buf][sl(24)*64]: 0-7 A-hi, 8-15 A-lo, 16-23 B-hi
    __shared__ float rstot_s[128];

    const int nb  = blockIdx.x;
    const int q   = gridDim.x >> 3;             // 64 (grid 512, %8==0)
    const int lg  = (nb & 7) * q + (nb >> 3);   // XCD-contiguous logical id
    const int mr  = lg & 15;
    const int nc  = lg >> 4;                    // 4 consecutive nc per XCD
    const int m0  = mr * 128, n0 = nc * 128;
    const int mtb0 = m0 >> 4;                   // 8 mt-tiles
    const int ntb0 = n0 >> 4;                   // 8 nt-tiles

    const int tid = threadIdx.x;
    const int l   = tid & 63;
    const int w   = __builtin_amdgcn_readfirstlane(tid >> 6);
    const int wm  = w & 1, wn = w >> 1;         // 2x2 waves: 64m x 64n each
    const int kq  = l >> 4, c = l & 15;

    // stage one 24KB K-step chunk into buffer buf_; 6 slices (1KB each) per wave
#define STAGE(s_, buf_)                                                              \
    {                                                                                \
        _Pragma("unroll")                                                            \
        for (int j = 0; j < 6; ++j) {                                                \
            const int sl = w * 6 + j;                                                \
            const bf16x8* gbase;                                                     \
            if (sl < 8)                                                              \
                gbase = Ahi + ((size_t)((mtb0 + sl) * 32 + 4 * (s_)) * 16);          \
            else if (sl < 16)                                                        \
                gbase = Alo + ((size_t)((mtb0 + sl - 8) * 32 + 4 * (s_)) * 16);      \
            else                                                                     \
                gbase = Bhi + ((size_t)((ntb0 + sl - 16) * 32 + 4 * (s_)) * 16);     \
            __builtin_amdgcn_global_load_lds(                                        \
                (const __attribute__((address_space(1))) unsigned*)(gbase + l),      \
                (__attribute__((address_space(3))) unsigned*)&smem[buf_][sl * 64],   \
                16, 0, 0);                                                           \
        }                                                                            \
    }

    f32x4 acc[4][4];
#pragma unroll
    for (int f = 0; f < 4; ++f)
#pragma unroll
        for (int nf = 0; nf < 4; ++nf) acc[f][nf] = f32x4{0.f, 0.f, 0.f, 0.f};

    STAGE(0, 0);
    if (tid < 128) {
        float ssum = 1.0f;
#pragma unroll
        for (int i = 0; i < NBLK; ++i) ssum += rowsum_p[(size_t)i * M + m0 + tid];
        rstot_s[tid] = ssum;
    }
    __syncthreads();

    for (int s = 0; s < 8; ++s) {
        if (s < 7) STAGE(s + 1, (s + 1) & 1);
        const bf16x8* sb = smem[s & 1];
        bf16x8 ah[4], al[4];
#pragma unroll
        for (int f = 0; f < 4; ++f) {
            ah[f] = sb[(wm * 4 + f) * 64 + l];
            al[f] = sb[512 + (wm * 4 + f) * 64 + l];
        }
#pragma unroll
        for (int nf = 0; nf < 4; ++nf) {
            bf16x8 bh = sb[1024 + (wn * 4 + nf) * 64 + l];
#pragma unroll
            for (int f = 0; f < 4; ++f) {
                acc[f][nf] = __builtin_amdgcn_mfma_f32_16x16x32_bf16(ah[f], bh, acc[f][nf], 0, 0, 0);
                acc[f][nf] = __builtin_amdgcn_mfma_f32_16x16x32_bf16(al[f], bh, acc[f][nf], 0, 0, 0);
            }
        }
        __syncthreads();
    }
#undef STAGE

    // epilogue: out[m][n] = acc + rstot[m]*bias[n]   (C/D: row=kq*4+reg, col=c)
#pragma unroll
    for (int f = 0; f < 4; ++f) {
        const int rloc = wm * 64 + f * 16 + kq * 4;
        const int rowb = m0 + rloc;
        float rsv[4];
#pragma unroll
        for (int reg = 0; reg < 4; ++reg) rsv[reg] = rstot_s[rloc + reg];
#pragma unroll
        for (int nf = 0; nf < 4; ++nf) {
            const int n = n0 + wn * 64 + nf * 16 + c;
            const float bv = bias[n];
#pragma unroll
            for (int reg = 0; reg < 4; ++reg)
                out[(size_t)(rowb + reg) * OUT_DIM + n] = acc[f][nf][reg] + rsv[reg] * bv;
        }
    }
}

extern "C" void kernel_launch(void* const* d_in, const int* in_sizes, int n_in,
                              void* d_out, int out_size, void* d_ws, size_t ws_size,
                              hipStream_t stream) {
    const float* x    = (const float*)d_in[0];
    const float* S    = (const float*)d_in[1];
    const float* U    = (const float*)d_in[2];
    const float* Vt   = (const float*)d_in[3];
    const float* bias = (const float*)d_in[4];
    float* out = (float*)d_out;
    const int M = in_sizes[0] / IN_DIM;   // 2048

    char* ws = (char*)d_ws;
    bf16x8* Bhi     = (bf16x8*)ws;                                    // 2 MB
    bf16x8* Ahi     = (bf16x8*)(ws + (2u << 20));                     // 1 MB
    bf16x8* Alo     = (bf16x8*)(ws + (3u << 20));                     // 1 MB
    float* rowsum_p = (float*)(ws + (4u << 20));                      // 128 KB

    fused_factor_pack<<<(M / 4) + 512, 256, 0, stream>>>(
        x, S, U, Vt, (bf16x4*)Ahi, (bf16x4*)Alo, Bhi, rowsum_p, M);
    apply_mfma<<<(M / 128) * (OUT_DIM / 128), 256, 0, stream>>>(
        Ahi, Alo, Bhi, rowsum_p, bias, out, M);
}

// Round 10
// 101.500 us; speedup vs baseline: 1.0823x; 1.0290x over previous
//
#include <hip/hip_runtime.h>

#define IN_DIM  4096
#define OUT_DIM 4096
#define RANK    16
#define NBLK    16
#define KDIM    256   // NBLK*RANK

typedef __attribute__((ext_vector_type(8))) _Float16 f16x8;
typedef __attribute__((ext_vector_type(4))) _Float16 f16x4;
typedef __attribute__((ext_vector_type(4))) float   f32x4;

// ---------------------------------------------------------------------------
// All operands single fp16 (magnitudes here are tiny: |x|<~7, |T|<~14,
// |Ahat|<~1.3 -> fp16's 10 mantissa bits beat split-bf16's 8+8 two-pass).
// Pack layouts (MFMA 16x16x32 fragment order), granularity = f16x8 (16B):
//   PackA[mt(128)][ko(32)][c(16)] : 8 f16 = T[mt*16+c][ko*8+j]    (A row=c)
//   PackB[nt(256)][ko(32)][c(16)] : 8 f16 = Ahat[ko*8+j][nt*16+c] (B col=c)
// apply GEMM: out = A @ B over K=256, fp32 accumulate.
// ---------------------------------------------------------------------------

// Fused: blocks [0, M/4)      : factor  T = x @ Vt-blocks  (fp16 MFMA)
//        blocks [M/4, M/4+512): B-pack  Ahat = S*U -> fp16 fragments
__global__ __launch_bounds__(256) void fused_factor_pack(const float* __restrict__ x,
                                                         const float* __restrict__ S,
                                                         const float* __restrict__ U,
                                                         const float* __restrict__ Vt,
                                                         f16x4* __restrict__ Apk4,
                                                         f16x8* __restrict__ Bpk,
                                                         float* __restrict__ rowsum_p,
                                                         int M) {
    const int nfac = M >> 2;   // 512 factor blocks
    const int blk  = blockIdx.x;
    const int tid  = threadIdx.x;

    if (blk < nfac) {
        // ---- factor: D[r][m] = sum_p Vt[i][p][r] * x[m][p]  (job = (mt, i)) ----
        const int l   = tid & 63;
        const int w   = tid >> 6;
        const int job = blk * 4 + w;
        const int i   = job & 15;
        const int mt  = job >> 4;
        const int row = l & 15;                 // m within tile (B col) / Vt r-col
        const int qt  = l >> 4;                 // k-quarter

        const float* xp  = x + (size_t)(mt * 16 + row) * IN_DIM + i * 256 + qt * 8;
        // Vt[i][qt*8 + ks*32 + j][row], j-stride = RANK floats
        const float* vtp = Vt + ((size_t)(i * 256 + qt * 8)) * RANK + row;

        f32x4 acc = {0.f, 0.f, 0.f, 0.f};
        float rs = 0.f;
#pragma unroll
        for (int ks = 0; ks < 8; ++ks) {
            float4 a = *reinterpret_cast<const float4*>(xp + ks * 32);
            float4 b = *reinterpret_cast<const float4*>(xp + ks * 32 + 4);
            rs += (a.x + a.y) + (a.z + a.w) + (b.x + b.y) + (b.z + b.w);
            f16x8 xf;
            xf[0] = (_Float16)a.x; xf[1] = (_Float16)a.y;
            xf[2] = (_Float16)a.z; xf[3] = (_Float16)a.w;
            xf[4] = (_Float16)b.x; xf[5] = (_Float16)b.y;
            xf[6] = (_Float16)b.z; xf[7] = (_Float16)b.w;
            f16x8 vf;
#pragma unroll
            for (int jj = 0; jj < 8; ++jj)
                vf[jj] = (_Float16)vtp[(size_t)(ks * 32 + jj) * RANK];
            acc = __builtin_amdgcn_mfma_f32_16x16x32_f16(vf, xf, acc, 0, 0, 0);
        }

        rs += __shfl_xor(rs, 16, 64);
        rs += __shfl_xor(rs, 32, 64);
        if (l < 16)
            rowsum_p[(size_t)i * M + mt * 16 + l] = rs;

        f16x4 hv;
#pragma unroll
        for (int reg = 0; reg < 4; ++reg) hv[reg] = (_Float16)acc[reg];
        size_t o4 = ((size_t)(mt * 32 + i * 2 + (l >> 5)) * 16 + row) * 2 + ((l >> 4) & 1);
        Apk4[o4] = hv;
    } else {
        // ---- B-pack: Ahat[(i,r)][(o,q)] = S[o,i,r]*U[o,r,q] -> fp16 ----
        int t  = (blk - nfac) * 256 + tid;  // = (nt*32 + ko)*16 + c
        int c  = t & 15;
        int ko = (t >> 4) & 31;
        int nt = t >> 9;
        int o  = nt >> 4;
        int i  = ko >> 1;
        int q  = ((nt & 15) << 4) | c;
        int r0 = (ko & 1) << 3;
        const float* Sp = S + ((o * NBLK + i) * RANK + r0);
        const float* Up = U + (size_t)o * RANK * 256 + q;   // + r*256
        f16x8 hv;
#pragma unroll
        for (int j = 0; j < 8; ++j)
            hv[j] = (_Float16)(Sp[j] * Up[(size_t)(r0 + j) * 256]);
        Bpk[t] = hv;
    }
}

// out = A @ B + (1+rowsum[m])*bias[n].
// Tile 128m x 128n, 512 blocks (>=2 blk/CU -> cross-block write/compute overlap),
// 4 waves (2x2, each 64m x 64n), K=256 in 8 steps of 32.
// LDS/step: A 8KB + B 8KB = 16KB; dbuf 32KB.
// Per wave per step: 16 MFMA : 8 ds_read_b128 : 4 global_load_lds.
__global__ __launch_bounds__(256, 3) void apply_mfma(const f16x8* __restrict__ Apk,
                                                     const f16x8* __restrict__ Bpk,
                                                     const float* __restrict__ rowsum_p,
                                                     const float* __restrict__ bias,
                                                     float* __restrict__ out, int M) {
    __shared__ f16x8 smem[2][1024];   // [buf][sl(16)*64]: 0-7 A, 8-15 B
    __shared__ float rstot_s[128];

    const int nb  = blockIdx.x;
    const int q   = gridDim.x >> 3;             // 64 (grid 512, %8==0)
    const int lg  = (nb & 7) * q + (nb >> 3);   // XCD-contiguous logical id
    const int mr  = lg & 15;
    const int nc  = lg >> 4;                    // 4 consecutive nc per XCD
    const int m0  = mr * 128, n0 = nc * 128;
    const int mtb0 = m0 >> 4;                   // 8 mt-tiles
    const int ntb0 = n0 >> 4;                   // 8 nt-tiles

    const int tid = threadIdx.x;
    const int l   = tid & 63;
    const int w   = __builtin_amdgcn_readfirstlane(tid >> 6);
    const int wm  = w & 1, wn = w >> 1;         // 2x2 waves: 64m x 64n each
    const int kq  = l >> 4, c = l & 15;

    // stage one 16KB K-step chunk into buffer buf_; 4 slices (1KB each) per wave
#define STAGE(s_, buf_)                                                              \
    {                                                                                \
        _Pragma("unroll")                                                            \
        for (int j = 0; j < 4; ++j) {                                                \
            const int sl = w * 4 + j;                                                \
            const f16x8* gbase;                                                      \
            if (sl < 8)                                                              \
                gbase = Apk + ((size_t)((mtb0 + sl) * 32 + 4 * (s_)) * 16);          \
            else                                                                     \
                gbase = Bpk + ((size_t)((ntb0 + sl - 8) * 32 + 4 * (s_)) * 16);      \
            __builtin_amdgcn_global_load_lds(                                        \
                (const __attribute__((address_space(1))) unsigned*)(gbase + l),      \
                (__attribute__((address_space(3))) unsigned*)&smem[buf_][sl * 64],   \
                16, 0, 0);                                                           \
        }                                                                            \
    }

    f32x4 acc[4][4];
#pragma unroll
    for (int f = 0; f < 4; ++f)
#pragma unroll
        for (int nf = 0; nf < 4; ++nf) acc[f][nf] = f32x4{0.f, 0.f, 0.f, 0.f};

    STAGE(0, 0);
    if (tid < 128) {
        float ssum = 1.0f;
#pragma unroll
        for (int i = 0; i < NBLK; ++i) ssum += rowsum_p[(size_t)i * M + m0 + tid];
        rstot_s[tid] = ssum;
    }
    __syncthreads();

    for (int s = 0; s < 8; ++s) {
        if (s < 7) STAGE(s + 1, (s + 1) & 1);
        const f16x8* sb = smem[s & 1];
        f16x8 af[4];
#pragma unroll
        for (int f = 0; f < 4; ++f)
            af[f] = sb[(wm * 4 + f) * 64 + l];
#pragma unroll
        for (int nf = 0; nf < 4; ++nf) {
            f16x8 bh = sb[512 + (wn * 4 + nf) * 64 + l];
#pragma unroll
            for (int f = 0; f < 4; ++f)
                acc[f][nf] = __builtin_amdgcn_mfma_f32_16x16x32_f16(af[f], bh, acc[f][nf], 0, 0, 0);
        }
        __syncthreads();
    }
#undef STAGE

    // epilogue: out[m][n] = acc + rstot[m]*bias[n]   (C/D: row=kq*4+reg, col=c)
#pragma unroll
    for (int f = 0; f < 4; ++f) {
        const int rloc = wm * 64 + f * 16 + kq * 4;
        const int rowb = m0 + rloc;
        float rsv[4];
#pragma unroll
        for (int reg = 0; reg < 4; ++reg) rsv[reg] = rstot_s[rloc + reg];
#pragma unroll
        for (int nf = 0; nf < 4; ++nf) {
            const int n = n0 + wn * 64 + nf * 16 + c;
            const float bv = bias[n];
#pragma unroll
            for (int reg = 0; reg < 4; ++reg)
                out[(size_t)(rowb + reg) * OUT_DIM + n] = acc[f][nf][reg] + rsv[reg] * bv;
        }
    }
}

extern "C" void kernel_launch(void* const* d_in, const int* in_sizes, int n_in,
                              void* d_out, int out_size, void* d_ws, size_t ws_size,
                              hipStream_t stream) {
    const float* x    = (const float*)d_in[0];
    const float* S    = (const float*)d_in[1];
    const float* U    = (const float*)d_in[2];
    const float* Vt   = (const float*)d_in[3];
    const float* bias = (const float*)d_in[4];
    float* out = (float*)d_out;
    const int M = in_sizes[0] / IN_DIM;   // 2048

    char* ws = (char*)d_ws;
    f16x8* Bpk      = (f16x8*)ws;                                     // 2 MB
    f16x8* Apk      = (f16x8*)(ws + (2u << 20));                      // 1 MB
    float* rowsum_p = (float*)(ws + (3u << 20));                      // 128 KB

    fused_factor_pack<<<(M / 4) + 512, 256, 0, stream>>>(
        x, S, U, Vt, (f16x4*)Apk, Bpk, rowsum_p, M);
    apply_mfma<<<(M / 128) * (OUT_DIM / 128), 256, 0, stream>>>(
        Apk, Bpk, rowsum_p, bias, out, M);
}